// Round 12
// baseline (455.947 us; speedup 1.0000x reference)
//
#include <hip/hip_runtime.h>
#include <math.h>

static constexpr int Bsz  = 16384;
static constexpr int Cdim = 1024;
static constexpr int Kdim = 128;
static constexpr int Vdim = 256;
static constexpr int HMd  = 512;
static constexpr int GOUTd= 1536;   // 4*384 gate hidden
static constexpr int GDIM = 1669;
static constexpr int GPAD = 1792;   // 1024 (ctx) + 768 (feats) all fp8, 14 x 128
static constexpr int F2D  = 704;    // fp16 feats2 width (11*64)
static constexpr int F8D  = 768;    // fp8 feats width (6*128)
static constexpr int Mdim = 1024;
static constexpr float TAU = 2e-3f; // fp16 score-gap ambiguity threshold (~13 sigma)

typedef __attribute__((ext_vector_type(8))) _Float16 f16x8;
typedef __attribute__((ext_vector_type(4))) _Float16 f16x4;
typedef __attribute__((ext_vector_type(4))) float f32x4;

__device__ __forceinline__ float sigm(float x){ return 1.0f/(1.0f+__expf(-x)); }
// exact-class gelu: erf via A&S 7.1.26 (max erf err 1.5e-7, far below fp16 rounding)
__device__ __forceinline__ float gelu(float x){
    float y = 0.70710678118654752440f * x;
    float a = fabsf(y);
    float t1 = __builtin_amdgcn_rcpf(fmaf(0.3275911f, a, 1.0f));
    float p = t1*fmaf(t1, fmaf(t1, fmaf(t1, fmaf(t1, 1.061405429f, -1.453152027f),
                                         1.421413741f), -0.284496736f), 0.254829592f);
    float e = __expf(-a*a);
    float er = fmaf(-p, e, 1.0f);
    er = (y < 0.0f) ? -er : er;
    return 0.5f*x*(1.0f+er);
}
__device__ __forceinline__ ushort f2h(float f){
    return __builtin_bit_cast(ushort, (_Float16)f);
}
// 4x f32 -> packed OCP e4m3 fp8 (gfx950 HW cvt)
__device__ __forceinline__ unsigned f2q4(float a, float b, float c, float d){
    int v = 0;
    v = __builtin_amdgcn_cvt_pk_fp8_f32(a, b, v, false);
    v = __builtin_amdgcn_cvt_pk_fp8_f32(c, d, v, true);
    return (unsigned)v;
}

// ============================ prep kernels ============================

__global__ __launch_bounds__(256) void k_zero(int* p){ if (threadIdx.x==0) *p = 0; }

__global__ __launch_bounds__(256) void k_cat(float* __restrict__ dst,
        const float* __restrict__ a, const float* __restrict__ b, int na, int ntot){
    int i = blockIdx.x*256 + threadIdx.x;
    if (i >= ntot) return;
    dst[i] = (i < na) ? a[i] : b[i-na];
}

// f32 [K,N] -> fp16 [N,K] tiled transpose
__global__ __launch_bounds__(256) void k_wt(const float* __restrict__ W,
                                            ushort* __restrict__ Wt, int K, int N){
    __shared__ float tile[64][65];
    int n0 = blockIdx.x*64, k0 = blockIdx.y*64;
    int tx = threadIdx.x & 63, ty = threadIdx.x >> 6;
    #pragma unroll
    for (int i=0;i<64;i+=4)
        tile[ty+i][tx] = W[(size_t)(k0+ty+i)*N + n0 + tx];
    __syncthreads();
    #pragma unroll
    for (int i=0;i<64;i+=4)
        Wt[(size_t)(n0+ty+i)*K + k0 + tx] = f2h(tile[tx][ty+i]);
}

// Wg1 ctx-part -> fp8 B8 [1536][1024], pre-swizzled 8B units (u ^= n&7 within 128B seg).
__global__ __launch_bounds__(256) void k_wg1t8(const float* __restrict__ Wg1,
                                               unsigned char* __restrict__ B8){
    __shared__ float tile[64][65];      // [f_local][h_local]
    int g  = blockIdx.z;
    int h0 = blockIdx.x*64;             // 6 blocks
    int f0 = blockIdx.y*64;             // 16 blocks (f < 1024 always valid)
    int tx = threadIdx.x & 63, ty = threadIdx.x >> 6;
    #pragma unroll
    for (int i=0;i<64;i+=4)
        tile[ty+i][tx] = Wg1[((size_t)g*GDIM + f0+ty+i)*384 + h0+tx];
    __syncthreads();
    int u = threadIdx.x & 7, nl0 = threadIdx.x >> 3;   // unit 0..7, row 0..31
    #pragma unroll
    for (int i=0;i<2;i++){
        int nl = nl0 + i*32;
        float v[8];
        #pragma unroll
        for (int j=0;j<8;j++) v[j] = tile[u*8+j][nl];
        unsigned q0 = f2q4(v[0],v[1],v[2],v[3]), q1 = f2q4(v[4],v[5],v[6],v[7]);
        int n  = g*384 + h0 + nl;
        int ur = (f0>>3) + u;
        int seg = ur >> 4, ul = ur & 15;
        size_t pos = (size_t)n*1024 + seg*128 + (size_t)(ul ^ (n&7))*8;
        ((unsigned*)(B8+pos))[0] = q0;
        ((unsigned*)(B8+pos))[1] = q1;
    }
}

// Wg1 feats-part -> fp8 [1536][768] pre-swizzled (f = 1024 + k; zero for f >= 1669)
__global__ __launch_bounds__(256) void k_wg1tf8(const float* __restrict__ Wg1,
                                                unsigned char* __restrict__ B8){
    __shared__ float tile[64][65];      // [k_local][h_local]
    int g  = blockIdx.z;
    int h0 = blockIdx.x*64;             // 6 blocks
    int k0 = blockIdx.y*64;             // 12 blocks (k < 768)
    int tx = threadIdx.x & 63, ty = threadIdx.x >> 6;
    #pragma unroll
    for (int i=0;i<64;i+=4){
        int f = 1024 + k0 + ty + i;
        tile[ty+i][tx] = (f < GDIM) ? Wg1[((size_t)g*GDIM + f)*384 + h0+tx] : 0.0f;
    }
    __syncthreads();
    int u = threadIdx.x & 7, nl0 = threadIdx.x >> 3;
    #pragma unroll
    for (int i=0;i<2;i++){
        int nl = nl0 + i*32;
        float v[8];
        #pragma unroll
        for (int j=0;j<8;j++) v[j] = tile[u*8+j][nl];
        unsigned q0 = f2q4(v[0],v[1],v[2],v[3]), q1 = f2q4(v[4],v[5],v[6],v[7]);
        int n  = g*384 + h0 + nl;
        int ur = (k0>>3) + u;           // unit 0..95
        int seg = ur >> 4, ul = ur & 15;
        size_t pos = (size_t)n*F8D + seg*128 + (size_t)(ul ^ (n&7))*8;
        ((unsigned*)(B8+pos))[0] = q0;
        ((unsigned*)(B8+pos))[1] = q1;
    }
}

// ctx f32 -> fp16 ctxh (linear) + fp8 ctx8 (pre-swizzled 8B units within 128B segs)
__global__ __launch_bounds__(256) void k_cvt8(const float* __restrict__ x,
        ushort* __restrict__ yh, unsigned char* __restrict__ y8, int nunits){
    int i = blockIdx.x*256 + threadIdx.x;        // one 8-elem unit
    if (i >= nunits) return;
    const float4* src = (const float4*)(x + (size_t)i*8);
    float4 v0 = src[0], v1 = src[1];
    ushort4 h0 = { f2h(v0.x), f2h(v0.y), f2h(v0.z), f2h(v0.w) };
    ushort4 h1 = { f2h(v1.x), f2h(v1.y), f2h(v1.z), f2h(v1.w) };
    ((ushort4*)yh)[(size_t)i*2]   = h0;
    ((ushort4*)yh)[(size_t)i*2+1] = h1;
    unsigned q0 = f2q4(v0.x,v0.y,v0.z,v0.w), q1 = f2q4(v1.x,v1.y,v1.z,v1.w);
    int row = i >> 7;            // 128 units/row (Cdim=1024)
    int ur  = i & 127;
    int seg = ur >> 4, ul = ur & 15;
    size_t pos = (size_t)row*1024 + seg*128 + (size_t)(ul ^ (row&7))*8;
    ((unsigned*)(y8+pos))[0] = q0;
    ((unsigned*)(y8+pos))[1] = q1;
}

// feats2 fp16 [CB][704] -> feats8 fp8 [CB][768] pre-swizzled (runs AFTER k_fixapply)
__global__ __launch_bounds__(256) void k_f2q8(const ushort* __restrict__ f16,
        unsigned char* __restrict__ f8, int total){
    int idx = blockIdx.x*256 + threadIdx.x;   // one 8B unit; 96 units/row
    if (idx >= total) return;
    int w = idx / 96, ur = idx - w*96;
    int c0 = ur*8;
    float v[8];
    #pragma unroll
    for (int j=0;j<8;j++){
        int c = c0+j;
        v[j] = (c < F2D) ? (float)(*(const _Float16*)&f16[(size_t)w*F2D + c]) : 0.0f;
    }
    unsigned q0 = f2q4(v[0],v[1],v[2],v[3]), q1 = f2q4(v[4],v[5],v[6],v[7]);
    int seg = ur >> 4, ul = ur & 15;
    size_t pos = (size_t)w*F8D + seg*128 + (size_t)(ul ^ (w&7))*8;
    ((unsigned*)(f8+pos))[0] = q0;
    ((unsigned*)(f8+pos))[1] = q1;
}

__device__ __forceinline__ void gload_lds16(const void* g, void* l){
    typedef __attribute__((address_space(1))) const unsigned gu32;
    typedef __attribute__((address_space(3))) unsigned lu32;
    __builtin_amdgcn_global_load_lds((gu32*)(unsigned long long)g,
                                     (lu32*)(unsigned)(unsigned long long)l,
                                     16, 0, 0);
}

// ============================ fp16 MFMA GEMM: 256x128 tile, 8 waves ============================
// (r9 proven structure; used for L1 / L2 / summary)
template<int ACT, int OUTM, int SRC, int NX>
__global__ __launch_bounds__(512, 4) void k_mgemm(const ushort* __restrict__ A,
        const ushort* __restrict__ A2, const ushort* __restrict__ Bt,
        const float* __restrict__ bias, const float* __restrict__ Wg2,
        void* __restrict__ Cout, int K, int lda){
    __shared__ alignas(16) ushort lds[24576];   // As[256][64] + Bs[128][64]
    ushort* As = lds;
    ushort* Bs = lds + 16384;
    int t = threadIdx.x;
    int l = t & 63, wv = t >> 6;
    int wrow = wv >> 1, wcol = wv & 1;
    int nwg = NX * (int)gridDim.y;
    int orig = (int)blockIdx.y * NX + (int)blockIdx.x;
    int qq = nwg >> 3, rr = nwg & 7;
    int xcd = orig & 7, loc = orig >> 3;
    int wgid = (xcd < rr ? xcd*(qq+1) : rr*(qq+1) + (xcd-rr)*qq) + loc;
    int bx = wgid % NX;
    int by = wgid / NX;
    size_t row0 = (size_t)by * 256;
    int col0 = bx * 128;
    constexpr int N = NX*128;
    f32x4 acc[4][4] = {};
    int lrow = l >> 3;
    int lc8  = (l & 7) ^ lrow;

    for (int k0 = 0; k0 < K; k0 += 64){
        const ushort* Ag; size_t astr; int koff;
        if (SRC == 2){
            Ag = A; astr = (size_t)lda; koff = k0 + (bx ? 512 : 0);
        } else { Ag = A; astr = (size_t)lda; koff = k0; }
        #pragma unroll
        for (int i = 0; i < 4; ++i){
            int ch = wv*4 + i;
            int r  = ch*8 + lrow;
            gload_lds16(Ag + (row0 + r)*astr + koff + lc8*8, As + ch*512);
        }
        #pragma unroll
        for (int i = 0; i < 2; ++i){
            int ch = wv*2 + i;
            int r  = ch*8 + lrow;
            gload_lds16(Bt + (size_t)(col0 + r)*K + k0 + lc8*8, Bs + ch*512);
        }
        __syncthreads();
        #pragma unroll
        for (int kk = 0; kk < 2; ++kk){
            f16x8 af[4], bfr[4];
            int j8 = kk*4 + (l >> 4);
            #pragma unroll
            for (int m = 0; m < 4; ++m){
                int row = wrow*64 + m*16 + (l & 15);
                int c16 = j8 ^ (row & 7);
                af[m] = *(const f16x8*)(const void*)(As + row*64 + c16*8);
            }
            #pragma unroll
            for (int n = 0; n < 4; ++n){
                int rowb = wcol*64 + n*16 + (l & 15);
                int c16 = j8 ^ (rowb & 7);
                bfr[n] = *(const f16x8*)(const void*)(Bs + rowb*64 + c16*8);
            }
            #pragma unroll
            for (int m = 0; m < 4; ++m)
                #pragma unroll
                for (int n = 0; n < 4; ++n)
                    acc[m][n] = __builtin_amdgcn_mfma_f32_16x16x32_f16(af[m], bfr[n], acc[m][n], 0, 0, 0);
        }
        __syncthreads();
    }
    int q = l >> 4, cf = l & 15;
    #pragma unroll
    for (int m = 0; m < 4; ++m){
        #pragma unroll
        for (int n = 0; n < 4; ++n){
            int col = col0 + wcol*64 + n*16 + cf;
            float bv = bias[col];
            #pragma unroll
            for (int i = 0; i < 4; ++i){
                size_t r = row0 + wrow*64 + m*16 + q*4 + i;
                float v = acc[m][n][i] + bv;
                if (ACT == 1) v = gelu(v);
                if (OUTM == 1) ((ushort*)Cout)[r*N + col] = f2h(v);
                else           ((float*) Cout)[r*N + col] = v;
            }
        }
    }
}

// ============================ gate GEMM: all-fp8, 14 K-tiles of 128 ============================
// 256x128 tile, 8 waves, r9 sync structure; A/B pre-swizzled 8B-granule fp8.
// Tiles 0..7: ctx (stride 1024); tiles 8..13: feats (stride 768). Fused gate head epilogue.
__global__ __launch_bounds__(512, 4) void k_ggemm(const unsigned char* __restrict__ A8,
        const unsigned char* __restrict__ F8, const unsigned char* __restrict__ B8,
        const unsigned char* __restrict__ BF8, const float* __restrict__ bias,
        const float* __restrict__ Wg2, float* __restrict__ part){
    __shared__ alignas(16) unsigned char lds[49152];   // A 32KB + B 16KB
    unsigned char* As8 = lds;
    unsigned char* Bs8 = lds + 32768;
    int t = threadIdx.x, l = t & 63, wv = t >> 6;
    int wrow = wv >> 1, wcol = wv & 1;
    constexpr int NX = 12;
    int nwg = NX * (int)gridDim.y;
    int orig = (int)blockIdx.y * NX + (int)blockIdx.x;
    int qq = nwg >> 3, rr = nwg & 7;
    int xcd = orig & 7, loc = orig >> 3;
    int wgid = (xcd < rr ? xcd*(qq+1) : rr*(qq+1) + (xcd-rr)*qq) + loc;
    int bx = wgid % NX;
    int by = wgid / NX;
    size_t row0 = (size_t)by * 256;
    int col0 = bx * 128;
    f32x4 acc[4][4] = {};
    int lrow = l >> 3;

    for (int kt = 0; kt < 14; ++kt){
        const unsigned char *Ab, *Bb; size_t astr; int koff;
        if (kt < 8){ Ab = A8; Bb = B8;  astr = 1024; koff = kt << 7; }
        else       { Ab = F8; Bb = BF8; astr = F8D;  koff = (kt-8) << 7; }
        #pragma unroll
        for (int i = 0; i < 4; ++i){
            int ch = wv*4 + i;
            int r  = ch*8 + lrow;
            gload_lds16(Ab + (row0 + r)*astr + koff + (l&7)*16, As8 + ch*1024);
        }
        #pragma unroll
        for (int i = 0; i < 2; ++i){
            int ch = wv*2 + i;
            int r  = ch*8 + lrow;
            gload_lds16(Bb + (size_t)(col0 + r)*astr + koff + (l&7)*16, Bs8 + ch*1024);
        }
        __syncthreads();
        #pragma unroll
        for (int kk = 0; kk < 4; ++kk){
            long a8[4], b8v[4];
            int j8 = (l >> 4) + kk*4;
            #pragma unroll
            for (int m = 0; m < 4; ++m){
                int row = wrow*64 + m*16 + (l & 15);
                int u = j8 ^ (row & 7);
                a8[m] = *(const long*)(const void*)(As8 + row*128 + u*8);
            }
            #pragma unroll
            for (int n = 0; n < 4; ++n){
                int col = wcol*64 + n*16 + (l & 15);
                int u = j8 ^ (col & 7);
                b8v[n] = *(const long*)(const void*)(Bs8 + col*128 + u*8);
            }
            #pragma unroll
            for (int m = 0; m < 4; ++m)
                #pragma unroll
                for (int n = 0; n < 4; ++n)
                    acc[m][n] = __builtin_amdgcn_mfma_f32_16x16x32_fp8_fp8(a8[m], b8v[n], acc[m][n], 0, 0, 0);
        }
        __syncthreads();
    }
    // ---- fused gate head epilogue ----
    int q = l >> 4, cf = l & 15;
    float* sacc = (float*)lds;          // [256]
    if (t < 256) sacc[t] = 0.f;
    __syncthreads();
    #pragma unroll
    for (int m = 0; m < 4; ++m){
        #pragma unroll
        for (int i = 0; i < 4; ++i){
            float v = 0.f;
            #pragma unroll
            for (int n = 0; n < 4; ++n){
                int col = col0 + wcol*64 + n*16 + cf;
                float z = acc[m][n][i] + bias[col];
                v += gelu(z) * Wg2[col];
            }
            atomicAdd(&sacc[wrow*64 + m*16 + q*4 + i], v);
        }
    }
    __syncthreads();
    if (t < 256) part[(row0 + t)*NX + bx] = sacc[t];
}

// ============================ f32 GEMM, dynamic M, persistent grid (fix path) ============================
// GATHER=1: A rows gathered on-the-fly via flaglist
template<int ACT, int GATHER>
__global__ __launch_bounds__(256) void k_gemm_dyn(const float* __restrict__ A,
                                                  const float* __restrict__ W,
                                                  const float* __restrict__ bias,
                                                  float* __restrict__ C,
                                                  const int* __restrict__ cntp,
                                                  const int* __restrict__ flaglist,
                                                  int b0, int N, int K){
    int cnt = *cntp;
    int M = (cnt + 63) & ~63;
    __shared__ float As[32][68];
    __shared__ float Ws[32][64];
    int t  = threadIdx.x;
    int tx = t & 15, ty = t >> 4;
    int col0 = blockIdx.x * 64;
    int ra = t >> 3;
    int ca = (t & 7) << 2;
    int rw = t >> 4;
    int cw = (t & 15) << 2;
    for (int row0 = (int)blockIdx.y*64; row0 < M; row0 += (int)gridDim.y*64){
        float acc[4][4] = {};
        const float *Arow0, *Arow1;
        if (GATHER){
            int r1 = row0 + ra, r2 = r1 + 32;
            int f1 = (r1 < cnt) ? flaglist[r1] : 0;
            int f2 = (r2 < cnt) ? flaglist[r2] : 0;
            Arow0 = A + ((size_t)b0 + f1)*K;
            Arow1 = A + ((size_t)b0 + f2)*K;
        } else {
            Arow0 = A + (size_t)(row0 + ra)*K;
            Arow1 = A + (size_t)(row0 + ra + 32)*K;
        }
        for (int k0 = 0; k0 < K; k0 += 32){
            float4 a0 = *(const float4*)(Arow0 + k0 + ca);
            float4 a1 = *(const float4*)(Arow1 + k0 + ca);
            float4 w0 = *(const float4*)(W + (size_t)(k0 + rw)*N + col0 + cw);
            float4 w1 = *(const float4*)(W + (size_t)(k0 + rw + 16)*N + col0 + cw);
            As[ca+0][ra] = a0.x; As[ca+1][ra] = a0.y; As[ca+2][ra] = a0.z; As[ca+3][ra] = a0.w;
            As[ca+0][ra+32] = a1.x; As[ca+1][ra+32] = a1.y; As[ca+2][ra+32] = a1.z; As[ca+3][ra+32] = a1.w;
            *(float4*)&Ws[rw][cw]    = w0;
            *(float4*)&Ws[rw+16][cw] = w1;
            __syncthreads();
            #pragma unroll
            for (int kk = 0; kk < 32; ++kk){
                float4 av = *(const float4*)&As[kk][ty*4];
                float4 wv = *(const float4*)&Ws[kk][tx*4];
                float a4[4] = {av.x, av.y, av.z, av.w};
                float w4[4] = {wv.x, wv.y, wv.z, wv.w};
                #pragma unroll
                for (int i=0;i<4;i++)
                    #pragma unroll
                    for (int j=0;j<4;j++)
                        acc[i][j] = fmaf(a4[i], w4[j], acc[i][j]);
            }
            __syncthreads();
        }
        #pragma unroll
        for (int i=0;i<4;i++){
            size_t r = (size_t)row0 + ty*4 + i;
            #pragma unroll
            for (int j=0;j<4;j++){
                int c = col0 + tx*4 + j;
                float v = acc[i][j] + bias[c];
                if (ACT == 1) v = gelu(v);
                C[r*N + c] = v;
            }
        }
    }
}

// per flagged row: normalize exact ck, rescore, patch ckc/feats2/bidx
__global__ __launch_bounds__(256) void k_fixapply(const float* __restrict__ fck,
        const float* __restrict__ keys, const float* __restrict__ values,
        const float* __restrict__ age,  const float* __restrict__ alive,
        float* __restrict__ ckc, ushort* __restrict__ feats2, int* __restrict__ bidx,
        const int* __restrict__ flagcnt, const int* __restrict__ flaglist, int b0){
    int i = (blockIdx.x<<2) + (threadIdx.x>>6);
    int lane = threadIdx.x & 63;
    if (i >= *flagcnt) return;
    int w = flaglist[i];
    size_t b = (size_t)b0 + w;
    float2 c2 = ((const float2*)(fck + (size_t)i*128))[lane];
    float ss = c2.x*c2.x + c2.y*c2.y;
    #pragma unroll
    for (int o=32;o;o>>=1) ss += __shfl_xor(ss,o);
    float inv = 1.0f / fmaxf(sqrtf(ss), 1e-6f);
    float2 cc; cc.x = c2.x*inv; cc.y = c2.y*inv;
    ((float2*)(ckc + (size_t)w*128))[lane] = cc;
    ushort* f2 = feats2 + (size_t)w*F2D;
    { ushort2 o = { f2h(cc.x), f2h(cc.y) };
      ((ushort2*)f2)[lane] = o; }
    float s1v = -1e30f; int bi = 0; int anylive = 0;
    #pragma unroll
    for (int s=0;s<6;s++){
        float a = alive[b*6+s];
        float2 k2 = ((const float2*)(keys + (b*6+s)*128))[lane];
        float ks = k2.x*k2.x + k2.y*k2.y;
        float dt = cc.x*k2.x + cc.y*k2.y;
        #pragma unroll
        for (int o=32;o;o>>=1){ ks += __shfl_xor(ks,o); dt += __shfl_xor(dt,o); }
        float sc;
        if (a > 0.0f){ sc = dt / fmaxf(sqrtf(ks), 1e-6f); anylive = 1; }
        else sc = -1e4f;
        if (sc > s1v){ s1v = sc; bi = s; }
    }
    int bis = anylive ? bi : 0;
    float bsc = anylive ? s1v : 0.0f;
    float4 mv = ((const float4*)(values + (b*6+bis)*256))[lane];
    ushort4 mo = { f2h(mv.x), f2h(mv.y), f2h(mv.z), f2h(mv.w) };
    ((ushort4*)(f2+384))[lane] = mo;
    if (lane == 0){
        bidx[w] = bis;
        float mage = age[b*6 + bis];
        f2[640] = f2h(bsc);
        f2[641] = f2h(sigm((mage - 8.0f)*0.125f));
        f2[642] = f2h(1.0f - bsc);
    }
}

// ---- slot match + feats2 build + ambiguity flagging ----
__global__ __launch_bounds__(256) void k_feats(
        const float* __restrict__ ledger, const float* __restrict__ keys,
        const float* __restrict__ values, const float* __restrict__ age,
        const float* __restrict__ alive,  const float* __restrict__ ckv,
        float* __restrict__ ckc, ushort* __restrict__ feats2,
        int* __restrict__ bidx, int* __restrict__ flagcnt, int* __restrict__ flaglist,
        int b0){
    int w = (blockIdx.x<<2) + (threadIdx.x>>6);
    int lane = threadIdx.x & 63;
    size_t b = (size_t)b0 + w;
    const float* ckr = ckv + (size_t)w*384;
    float2 cr2 = ((const float2*)ckr)[lane];
    float ssc = cr2.x*cr2.x + cr2.y*cr2.y;
    #pragma unroll
    for (int o=32;o;o>>=1) ssc += __shfl_xor(ssc,o);
    float invc = 1.0f / fmaxf(sqrtf(ssc), 1e-6f);
    float2 cc; cc.x = cr2.x*invc; cc.y = cr2.y*invc;
    ((float2*)(ckc + (size_t)w*128))[lane] = cc;
    float s1v = -1e30f, s2v = -1e30f; int bi = 0; int anylive = 0;
    #pragma unroll
    for (int s=0;s<6;s++){
        float a = alive[b*6+s];
        float2 k2 = ((const float2*)(keys + (b*6+s)*128))[lane];
        float ss = k2.x*k2.x + k2.y*k2.y;
        float dt = cc.x*k2.x + cc.y*k2.y;
        #pragma unroll
        for (int o=32;o;o>>=1){ ss += __shfl_xor(ss,o); dt += __shfl_xor(dt,o); }
        float sc;
        if (a > 0.0f){ sc = dt / fmaxf(sqrtf(ss), 1e-6f); anylive = 1; }
        else sc = -1e4f;
        if (sc > s1v){ s2v = s1v; s1v = sc; bi = s; }
        else if (sc > s2v) s2v = sc;
    }
    float best_score = anylive ? s1v : 0.0f;
    int bis = anylive ? bi : 0;
    if (lane == 0 && (s1v - s2v) < TAU){
        int pos = atomicAdd(flagcnt, 1);
        flaglist[pos] = w;
    }
    float4 mv = ((const float4*)(values + (b*6+bis)*256))[lane];
    float mage = age[b*6+bis];
    float cad = sigm((mage - 8.0f)*0.125f);
    ushort* f2 = feats2 + (size_t)w*F2D;
    { ushort2 o = { f2h(cc.x), f2h(cc.y) };
      ((ushort2*)f2)[lane] = o; }
    { float4 v = ((const float4*)(ckr+128))[lane];
      ushort4 o = { f2h(v.x), f2h(v.y), f2h(v.z), f2h(v.w) };
      ((ushort4*)(f2+128))[lane] = o; }
    { ushort4 o = { f2h(mv.x), f2h(mv.y), f2h(mv.z), f2h(mv.w) };
      ((ushort4*)(f2+384))[lane] = o; }
    if (lane == 0){
        f2[640] = f2h(best_score);
        f2[641] = f2h(cad);
        f2[642] = f2h(1.0f - best_score);
        f2[643] = f2h(ledger[b*2]);
        f2[644] = f2h(ledger[b*2+1]);
        bidx[w] = bis;
    }
    if (lane < F2D - 645) f2[645+lane] = 0;   // zero pad 645..703
}

// ---- gates (from part), spawn select, scatter update, summary ----
__global__ __launch_bounds__(256) void k_update(const float* __restrict__ keys,
        const float* __restrict__ values, const float* __restrict__ conf,
        const float* __restrict__ age,    const float* __restrict__ alive,
        const float* __restrict__ ckC,    const float* __restrict__ ckv,
        const float* __restrict__ part,   const float* __restrict__ bg2,
        const int* __restrict__ bidx,
        float* __restrict__ probsC,
        float* __restrict__ o_keys, float* __restrict__ o_vals,
        float* __restrict__ o_conf, float* __restrict__ o_age,
        float* __restrict__ o_aliv, float* __restrict__ o_sum,
        ushort* __restrict__ o_sumb, int b0){
    int w = (blockIdx.x<<2) + (threadIdx.x>>6);
    int lane = threadIdx.x & 63;
    size_t b = (size_t)b0 + w;
    const float* pp = part + (size_t)w*12;
    float pb[4];
    #pragma unroll
    for (int g=0; g<4; ++g)
        pb[g] = sigm(pp[3*g] + pp[3*g+1] + pp[3*g+2] + bg2[g]);
    if (lane < 4) probsC[w*4 + lane] = pb[lane];
    float rp = pb[0], sp = pb[1], tp = pb[3];
    float al[6], cf[6], ag[6];
    float hl = 0.f;
    #pragma unroll
    for (int s=0;s<6;s++){
        al[s]=alive[b*6+s]; cf[s]=conf[b*6+s]; ag[s]=age[b*6+s];
        hl = fmaxf(hl, al[s]);
    }
    float rr = hl * sigm((rp-0.55f)*4.0f);
    float sr = sigm((sp-0.60f)*4.0f);
    float den = 1.0f + rr + sr;
    float refresh = rr/den, spawn = sr/den;
    float retire = sigm((tp-0.15f)*4.0f);
    int bi = bidx[w];
    int ic = -1;
    #pragma unroll
    for (int s=5;s>=0;s--) if (al[s] < 0.5f) ic = s;
    int si;
    if (ic >= 0) si = ic;
    else {
        float bu = 1e30f; int am = 0;
        #pragma unroll
        for (int s=0;s<6;s++){
            float u = (s == bi) ? 1e4f : (cf[s] - 0.01f*ag[s]);
            if (u < bu){ bu = u; am = s; }
        }
        si = am;
    }
    float2 cc  = ((const float2*)(ckC + (size_t)w*128))[lane];
    float4 cvv = ((const float4*)(ckv + (size_t)w*384 + 128))[lane];
    float s0=0,s1=0,s2=0,s3=0, wsum=0;
    #pragma unroll
    for (int s=0;s<6;s++){
        float wr = refresh*(s==bi ? 1.0f:0.0f) + spawn*(s==si ? 1.0f:0.0f);
        wr = fminf(wr, 1.0f);
        float rs = (s==bi) ? retire : 0.0f;
        float om = 1.0f - wr;
        float2 k2 = ((const float2*)(keys + (b*6+s)*128))[lane];
        float2 kn; kn.x = k2.x*om + wr*cc.x; kn.y = k2.y*om + wr*cc.y;
        ((float2*)(o_keys + (b*6+s)*128))[lane] = kn;
        float4 vv = ((const float4*)(values + (b*6+s)*256))[lane];
        float4 vn;
        vn.x = vv.x*om + wr*cvv.x; vn.y = vv.y*om + wr*cvv.y;
        vn.z = vv.z*om + wr*cvv.z; vn.w = vv.w*om + wr*cvv.w;
        ((float4*)(o_vals + (b*6+s)*256))[lane] = vn;
        float cn  = (cf[s]*0.995f*om + wr) * (1.0f - rs);
        float an  = fminf(fmaxf(al[s]*(1.0f - rs) + wr, 0.0f), 1.0f);
        float agn = (ag[s] + al[s]) * om;
        float wgt = an * cn;
        wsum += wgt;
        s0 += vn.x*wgt; s1 += vn.y*wgt; s2 += vn.z*wgt; s3 += vn.w*wgt;
        if (lane == s){ o_conf[b*6+s] = cn; o_age[b*6+s] = agn; o_aliv[b*6+s] = an; }
    }
    float inv = 1.0f/(wsum + 1e-6f);
    float4 sm; sm.x = s0*inv; sm.y = s1*inv; sm.z = s2*inv; sm.w = s3*inv;
    ((float4*)(o_sum + b*256))[lane] = sm;
    ushort4 sb = { f2h(sm.x), f2h(sm.y), f2h(sm.z), f2h(sm.w) };
    ((ushort4*)(o_sumb + (size_t)w*256))[lane] = sb;
}

// ---- layernorm + promote (fp16 z in) ----
__global__ __launch_bounds__(256) void k_ln(const ushort* __restrict__ z,
        const float* __restrict__ probs, const float* __restrict__ g_ln,
        const float* __restrict__ b_ln,  float* __restrict__ o_prom, int b0){
    int w = blockIdx.x; int t = threadIdx.x;
    int lane = t & 63, wid = t >> 6;
    f16x4 hv = ((const f16x4*)(z + (size_t)w*1024))[t];
    float v0 = (float)hv[0], v1 = (float)hv[1], v2 = (float)hv[2], v3 = (float)hv[3];
    float s = v0+v1+v2+v3;
    #pragma unroll
    for (int o=32;o;o>>=1) s += __shfl_xor(s,o);
    __shared__ float red[4];
    if (lane==0) red[wid] = s;
    __syncthreads();
    float mu = (red[0]+red[1]+red[2]+red[3]) * (1.0f/1024.0f);
    float d0=v0-mu, d1=v1-mu, d2=v2-mu, d3=v3-mu;
    float ss = d0*d0+d1*d1+d2*d2+d3*d3;
    #pragma unroll
    for (int o=32;o;o>>=1) ss += __shfl_xor(ss,o);
    __syncthreads();
    if (lane==0) red[wid] = ss;
    __syncthreads();
    float var = (red[0]+red[1]+red[2]+red[3]) * (1.0f/1024.0f);
    float rstd = 1.0f / sqrtf(var + 1e-5f);
    float pm = sigm((probs[w*4+2]-0.50f)*4.0f);
    float4 g  = ((const float4*)g_ln)[t];
    float4 bb = ((const float4*)b_ln)[t];
    float4 o;
    o.x = pm*(d0*rstd*g.x + bb.x);
    o.y = pm*(d1*rstd*g.y + bb.y);
    o.z = pm*(d2*rstd*g.z + bb.z);
    o.w = pm*(d3*rstd*g.w + bb.w);
    ((float4*)(o_prom + ((size_t)b0 + w)*1024))[t] = o;
}

extern "C" void kernel_launch(void* const* d_in, const int* in_sizes, int n_in,
                              void* d_out, int out_size, void* d_ws, size_t ws_size,
                              hipStream_t stream){
    const float* ctx    = (const float*)d_in[0];
    const float* ledger = (const float*)d_in[1];
    const float* keys   = (const float*)d_in[2];
    const float* values = (const float*)d_in[3];
    const float* conf   = (const float*)d_in[4];
    const float* age    = (const float*)d_in[5];
    const float* alive  = (const float*)d_in[6];
    const float* Wk1 = (const float*)d_in[7];  const float* bk1 = (const float*)d_in[8];
    const float* Wk2 = (const float*)d_in[9];  const float* bk2 = (const float*)d_in[10];
    const float* Wv1 = (const float*)d_in[11]; const float* bv1 = (const float*)d_in[12];
    const float* Wv2 = (const float*)d_in[13]; const float* bv2 = (const float*)d_in[14];
    const float* Wg1 = (const float*)d_in[15]; const float* bg1 = (const float*)d_in[16];
    const float* Wg2 = (const float*)d_in[17]; const float* bg2 = (const float*)d_in[18];
    const float* Wsum= (const float*)d_in[19]; const float* bsum= (const float*)d_in[20];
    const float* g_ln= (const float*)d_in[21]; const float* b_ln= (const float*)d_in[22];

    float* out   = (float*)d_out;
    float* o_prom= out;
    float* o_sum = o_prom + (size_t)Bsz*Mdim;
    float* o_keys= o_sum  + (size_t)Bsz*Vdim;
    float* o_vals= o_keys + (size_t)Bsz*6*Kdim;
    float* o_conf= o_vals + (size_t)Bsz*6*Vdim;
    float* o_age = o_conf + (size_t)Bsz*6;
    float* o_aliv= o_age  + (size_t)Bsz*6;

    // ---------- workspace layout ----------
    char* p = (char*)d_ws;
    auto alloc = [&](size_t bytes)->char*{
        char* r = p; p += (bytes + 255) & ~(size_t)255; return r;
    };
    ushort* ctxh  = (ushort*)alloc((size_t)Bsz*Cdim*2);           // fp16 ctx
    unsigned char* ctx8 = (unsigned char*)alloc((size_t)Bsz*Cdim);// fp8 ctx, pre-swizzled
    ushort* W1m   = (ushort*)alloc((size_t)1024*Cdim*2);          // [Wk1t|Wv1t]
    ushort* W2m   = (ushort*)alloc((size_t)384*HMd*2);            // [Wk2t|Wv2t]
    unsigned char* Wg1t8  = (unsigned char*)alloc((size_t)GOUTd*1024); // fp8 gate ctx-part
    unsigned char* Wg1tf8 = (unsigned char*)alloc((size_t)GOUTd*F8D);  // fp8 gate feats-part
    ushort* Wsumt = (ushort*)alloc((size_t)Mdim*Vdim*2);
    float*  biasm1= (float*) alloc(1024*4);
    float*  biasm2= (float*) alloc(384*4);
    size_t fixed = (size_t)(p - (char*)d_ws);
    size_t per_row = 2048 + 1536 + 512 + 1408 + 768 + 48 + 4096 + 512 + 16
                   + 4 + 4 + 2048 + 512 + 160;
    int CB = 16384;
    while (CB > 256 && fixed + (size_t)CB*per_row + 16384 > ws_size) CB >>= 1;
    ushort* H      = (ushort*)alloc((size_t)CB*1024*2);   // [Hk|Hv] fp16
    float*  ckv    = (float*) alloc((size_t)CB*384*4);    // [ckraw|cv] f32
    float*  ckc    = (float*) alloc((size_t)CB*Kdim*4);
    ushort* feats2 = (ushort*)alloc((size_t)CB*F2D*2);
    unsigned char* feats8 = (unsigned char*)alloc((size_t)CB*F8D);
    float*  part   = (float*) alloc((size_t)CB*12*4);
    float*  zbuf   = (float*) alloc((size_t)CB*Mdim*4);
    ushort* sumb   = (ushort*)alloc((size_t)CB*Vdim*2);
    float*  probsC = (float*) alloc((size_t)CB*4*4);
    int*    bidxC  = (int*)   alloc((size_t)CB*4);
    int*    flagl  = (int*)   alloc((size_t)CB*4);
    int*    flagc  = (int*)   alloc(256);
    float*  fH     = (float*) alloc((size_t)CB*HMd*4);
    float*  fck    = (float*) alloc((size_t)CB*Kdim*4);
    ushort* zh     = (ushort*)zbuf;   // fp16 z view

    dim3 blk(256);
    dim3 blk512(512);
    // ---------- prep ----------
    k_cvt8<<<(int)(((size_t)Bsz*Cdim/8 + 255)/256), blk, 0, stream>>>(
        ctx, ctxh, ctx8, (int)((size_t)Bsz*Cdim/8));
    k_wt<<<dim3(HMd/64,  Cdim/64), blk, 0, stream>>>(Wk1, W1m,             Cdim, HMd);
    k_wt<<<dim3(HMd/64,  Cdim/64), blk, 0, stream>>>(Wv1, W1m + 512*Cdim,  Cdim, HMd);
    k_wt<<<dim3(Kdim/64, HMd/64),  blk, 0, stream>>>(Wk2, W2m,             HMd, Kdim);
    k_wt<<<dim3(Vdim/64, HMd/64),  blk, 0, stream>>>(Wv2, W2m + 128*HMd,   HMd, Vdim);
    k_wt<<<dim3(Mdim/64, Vdim/64), blk, 0, stream>>>(Wsum, Wsumt, Vdim, Mdim);
    k_wg1t8<<<dim3(6, 16, 4), blk, 0, stream>>>(Wg1, Wg1t8);
    k_wg1tf8<<<dim3(6, 12, 4), blk, 0, stream>>>(Wg1, Wg1tf8);
    k_cat<<<(1024+255)/256, blk, 0, stream>>>(biasm1, bk1, bv1, 512, 1024);
    k_cat<<<(384+255)/256,  blk, 0, stream>>>(biasm2, bk2, bv2, 128, 384);

    for (int b0 = 0; b0 < Bsz; b0 += CB){
        k_zero<<<1, blk, 0, stream>>>(flagc);
        // merged L1: H = gelu(ctx @ [Wk1|Wv1] + [bk1|bv1]), fp16 out
        k_mgemm<1,1,0,8><<<dim3(8, CB/256), blk512, 0, stream>>>(
            ctxh + (size_t)b0*Cdim, nullptr, W1m, biasm1, nullptr, H, Cdim, Cdim);
        // merged L2: ckv = [Hk@Wk2+bk2 | Hv@Wv2+bv2], f32 out
        k_mgemm<0,0,2,3><<<dim3(3, CB/256), blk512, 0, stream>>>(
            H, nullptr, W2m, biasm2, nullptr, ckv, HMd, 1024);
        // slot match + feats2 + flags
        k_feats<<<CB/4, blk, 0, stream>>>(ledger, keys, values, age, alive,
                                          ckv, ckc, feats2, bidxC, flagc, flagl, b0);
        // exact f32 recompute of ambiguous rows (gathered A, persistent grids)
        k_gemm_dyn<1,1><<<dim3(HMd/64, 16), blk, 0, stream>>>(
            ctx, Wk1, bk1, fH, flagc, flagl, b0, HMd, Cdim);
        k_gemm_dyn<0,0><<<dim3(Kdim/64, 16), blk, 0, stream>>>(
            fH, Wk2, bk2, fck, flagc, nullptr, 0, Kdim, HMd);
        k_fixapply<<<CB/4, blk, 0, stream>>>(fck, keys, values, age, alive,
                                             ckc, feats2, bidxC, flagc, flagl, b0);
        // feats2 (patched) -> fp8 pre-swizzled feats8
        k_f2q8<<<(CB*96 + 255)/256, blk, 0, stream>>>(feats2, feats8, CB*96);
        // gate GEMM (all fp8, 14 K-tiles) with fused head: part[b,12]
        k_ggemm<<<dim3(12, CB/256), blk512, 0, stream>>>(
            ctx8 + (size_t)b0*Cdim, feats8, Wg1t8, Wg1tf8, bg1, Wg2, part);
        // gates + scatter update + summary
        k_update<<<CB/4, blk, 0, stream>>>(keys, values, conf, age, alive, ckc, ckv,
                                           part, bg2, bidxC, probsC,
                                           o_keys, o_vals, o_conf, o_age, o_aliv,
                                           o_sum, sumb, b0);
        // summary projection (fp16 z out) + LN + promote
        k_mgemm<0,1,0,8><<<dim3(8, CB/256), blk512, 0, stream>>>(
            sumb, nullptr, Wsumt, bsum, nullptr, zh, Vdim, Vdim);
        k_ln<<<CB, blk, 0, stream>>>(zh, probsC, g_ln, b_ln, o_prom, b0);
    }
}

// Round 13
// 443.341 us; speedup vs baseline: 1.0284x; 1.0284x over previous
//
#include <hip/hip_runtime.h>
#include <math.h>

static constexpr int Bsz  = 16384;
static constexpr int Cdim = 1024;
static constexpr int Kdim = 128;
static constexpr int Vdim = 256;
static constexpr int HMd  = 512;
static constexpr int GOUTd= 1536;   // 4*384 gate hidden
static constexpr int GDIM = 1669;
static constexpr int GPAD = 1728;   // 1024 (ctx, fp8) + 704 (feats2, fp16)
static constexpr int F2D  = 704;    // feats2 width = 11*64
static constexpr int Mdim = 1024;
static constexpr float TAU = 2e-3f; // fp16 score-gap ambiguity threshold (~13 sigma)

typedef __attribute__((ext_vector_type(8))) _Float16 f16x8;
typedef __attribute__((ext_vector_type(4))) _Float16 f16x4;
typedef __attribute__((ext_vector_type(4))) float f32x4;

__device__ __forceinline__ float sigm(float x){ return 1.0f/(1.0f+__expf(-x)); }
// exact-class gelu: erf via A&S 7.1.26 (max erf err 1.5e-7, far below fp16 rounding)
__device__ __forceinline__ float gelu(float x){
    float y = 0.70710678118654752440f * x;
    float a = fabsf(y);
    float t1 = __builtin_amdgcn_rcpf(fmaf(0.3275911f, a, 1.0f));
    float p = t1*fmaf(t1, fmaf(t1, fmaf(t1, fmaf(t1, 1.061405429f, -1.453152027f),
                                         1.421413741f), -0.284496736f), 0.254829592f);
    float e = __expf(-a*a);
    float er = fmaf(-p, e, 1.0f);
    er = (y < 0.0f) ? -er : er;
    return 0.5f*x*(1.0f+er);
}
__device__ __forceinline__ ushort f2h(float f){
    return __builtin_bit_cast(ushort, (_Float16)f);
}
// 4x f32 -> packed OCP e4m3 fp8 (gfx950 HW cvt)
__device__ __forceinline__ unsigned f2q4(float a, float b, float c, float d){
    int v = 0;
    v = __builtin_amdgcn_cvt_pk_fp8_f32(a, b, v, false);
    v = __builtin_amdgcn_cvt_pk_fp8_f32(c, d, v, true);
    return (unsigned)v;
}

// ============================ prep kernels ============================

__global__ __launch_bounds__(256) void k_zero(int* p){ if (threadIdx.x==0) *p = 0; }

__global__ __launch_bounds__(256) void k_cat(float* __restrict__ dst,
        const float* __restrict__ a, const float* __restrict__ b, int na, int ntot){
    int i = blockIdx.x*256 + threadIdx.x;
    if (i >= ntot) return;
    dst[i] = (i < na) ? a[i] : b[i-na];
}

// f32 [K,N] -> fp16 [N,K] tiled transpose
__global__ __launch_bounds__(256) void k_wt(const float* __restrict__ W,
                                            ushort* __restrict__ Wt, int K, int N){
    __shared__ float tile[64][65];
    int n0 = blockIdx.x*64, k0 = blockIdx.y*64;
    int tx = threadIdx.x & 63, ty = threadIdx.x >> 6;
    #pragma unroll
    for (int i=0;i<64;i+=4)
        tile[ty+i][tx] = W[(size_t)(k0+ty+i)*N + n0 + tx];
    __syncthreads();
    #pragma unroll
    for (int i=0;i<64;i+=4)
        Wt[(size_t)(n0+ty+i)*K + k0 + tx] = f2h(tile[tx][ty+i]);
}

// Wg1 ctx-part -> fp8 B8 [1536][1024], pre-swizzled 8B units (u ^= n&7 within 128B seg).
// LDS-tiled: coalesced reads along h; 8B-granule writes within contiguous 128B segs.
__global__ __launch_bounds__(256) void k_wg1t8(const float* __restrict__ Wg1,
                                               unsigned char* __restrict__ B8){
    __shared__ float tile[64][65];      // [f_local][h_local]
    int g  = blockIdx.z;
    int h0 = blockIdx.x*64;             // 6 blocks
    int f0 = blockIdx.y*64;             // 16 blocks (f < 1024 always valid)
    int tx = threadIdx.x & 63, ty = threadIdx.x >> 6;
    #pragma unroll
    for (int i=0;i<64;i+=4)
        tile[ty+i][tx] = Wg1[((size_t)g*GDIM + f0+ty+i)*384 + h0+tx];
    __syncthreads();
    int u = threadIdx.x & 7, nl0 = threadIdx.x >> 3;   // unit 0..7, row 0..31
    #pragma unroll
    for (int i=0;i<2;i++){
        int nl = nl0 + i*32;
        float v[8];
        #pragma unroll
        for (int j=0;j<8;j++) v[j] = tile[u*8+j][nl];
        unsigned q0 = f2q4(v[0],v[1],v[2],v[3]), q1 = f2q4(v[4],v[5],v[6],v[7]);
        int n  = g*384 + h0 + nl;
        int ur = (f0>>3) + u;
        int seg = ur >> 4, ul = ur & 15;
        size_t pos = (size_t)n*1024 + seg*128 + (size_t)(ul ^ (n&7))*8;
        ((unsigned*)(B8+pos))[0] = q0;
        ((unsigned*)(B8+pos))[1] = q1;
    }
}

// Wg1 feats-part -> fp16 [1536][704] (f = 1024+k; zero for f>=1669). LDS-tiled, both sides coalesced.
__global__ __launch_bounds__(256) void k_wg1tf(const float* __restrict__ Wg1,
                                               ushort* __restrict__ Wt){
    __shared__ float tile[64][65];
    int g  = blockIdx.z;
    int h0 = blockIdx.x*64;             // 6 blocks
    int k0 = blockIdx.y*64;             // 11 blocks
    int tx = threadIdx.x & 63, ty = threadIdx.x >> 6;
    #pragma unroll
    for (int i=0;i<64;i+=4){
        int f = 1024 + k0 + ty + i;
        tile[ty+i][tx] = (f < GDIM) ? Wg1[((size_t)g*GDIM + f)*384 + h0+tx] : 0.0f;
    }
    __syncthreads();
    #pragma unroll
    for (int i=0;i<64;i+=4)
        Wt[((size_t)(g*384 + h0+ty+i))*F2D + k0 + tx] = f2h(tile[tx][ty+i]);
}

// ctx f32 -> fp16 ctxh (linear) + fp8 ctx8 (pre-swizzled 8B units within 128B segs)
__global__ __launch_bounds__(256) void k_cvt8(const float* __restrict__ x,
        ushort* __restrict__ yh, unsigned char* __restrict__ y8, int nunits){
    int i = blockIdx.x*256 + threadIdx.x;        // one 8-elem unit
    if (i >= nunits) return;
    const float4* src = (const float4*)(x + (size_t)i*8);
    float4 v0 = src[0], v1 = src[1];
    ushort4 h0 = { f2h(v0.x), f2h(v0.y), f2h(v0.z), f2h(v0.w) };
    ushort4 h1 = { f2h(v1.x), f2h(v1.y), f2h(v1.z), f2h(v1.w) };
    ((ushort4*)yh)[(size_t)i*2]   = h0;
    ((ushort4*)yh)[(size_t)i*2+1] = h1;
    unsigned q0 = f2q4(v0.x,v0.y,v0.z,v0.w), q1 = f2q4(v1.x,v1.y,v1.z,v1.w);
    int row = i >> 7;            // 128 units/row (Cdim=1024)
    int ur  = i & 127;
    int seg = ur >> 4, ul = ur & 15;
    size_t pos = (size_t)row*1024 + seg*128 + (size_t)(ul ^ (row&7))*8;
    ((unsigned*)(y8+pos))[0] = q0;
    ((unsigned*)(y8+pos))[1] = q1;
}

__device__ __forceinline__ void gload_lds16(const void* g, void* l){
    typedef __attribute__((address_space(1))) const unsigned gu32;
    typedef __attribute__((address_space(3))) unsigned lu32;
    __builtin_amdgcn_global_load_lds((gu32*)(unsigned long long)g,
                                     (lu32*)(unsigned)(unsigned long long)l,
                                     16, 0, 0);
}

// ============================ fp16 MFMA GEMM: 256x128 tile, 8 waves ============================
// (r9 proven structure; used for L1 / L2 / summary)
template<int ACT, int OUTM, int SRC, int NX>
__global__ __launch_bounds__(512, 4) void k_mgemm(const ushort* __restrict__ A,
        const ushort* __restrict__ A2, const ushort* __restrict__ Bt,
        const float* __restrict__ bias, const float* __restrict__ Wg2,
        void* __restrict__ Cout, int K, int lda){
    __shared__ alignas(16) ushort lds[24576];   // As[256][64] + Bs[128][64]
    ushort* As = lds;
    ushort* Bs = lds + 16384;
    int t = threadIdx.x;
    int l = t & 63, wv = t >> 6;
    int wrow = wv >> 1, wcol = wv & 1;
    int nwg = NX * (int)gridDim.y;
    int orig = (int)blockIdx.y * NX + (int)blockIdx.x;
    int qq = nwg >> 3, rr = nwg & 7;
    int xcd = orig & 7, loc = orig >> 3;
    int wgid = (xcd < rr ? xcd*(qq+1) : rr*(qq+1) + (xcd-rr)*qq) + loc;
    int bx = wgid % NX;
    int by = wgid / NX;
    size_t row0 = (size_t)by * 256;
    int col0 = bx * 128;
    constexpr int N = NX*128;
    f32x4 acc[4][4] = {};
    int lrow = l >> 3;
    int lc8  = (l & 7) ^ lrow;

    for (int k0 = 0; k0 < K; k0 += 64){
        const ushort* Ag; size_t astr; int koff;
        if (SRC == 2){
            Ag = A; astr = (size_t)lda; koff = k0 + (bx ? 512 : 0);
        } else { Ag = A; astr = (size_t)lda; koff = k0; }
        #pragma unroll
        for (int i = 0; i < 4; ++i){
            int ch = wv*4 + i;
            int r  = ch*8 + lrow;
            gload_lds16(Ag + (row0 + r)*astr + koff + lc8*8, As + ch*512);
        }
        #pragma unroll
        for (int i = 0; i < 2; ++i){
            int ch = wv*2 + i;
            int r  = ch*8 + lrow;
            gload_lds16(Bt + (size_t)(col0 + r)*K + k0 + lc8*8, Bs + ch*512);
        }
        __syncthreads();
        #pragma unroll
        for (int kk = 0; kk < 2; ++kk){
            f16x8 af[4], bfr[4];
            int j8 = kk*4 + (l >> 4);
            #pragma unroll
            for (int m = 0; m < 4; ++m){
                int row = wrow*64 + m*16 + (l & 15);
                int c16 = j8 ^ (row & 7);
                af[m] = *(const f16x8*)(const void*)(As + row*64 + c16*8);
            }
            #pragma unroll
            for (int n = 0; n < 4; ++n){
                int rowb = wcol*64 + n*16 + (l & 15);
                int c16 = j8 ^ (rowb & 7);
                bfr[n] = *(const f16x8*)(const void*)(Bs + rowb*64 + c16*8);
            }
            #pragma unroll
            for (int m = 0; m < 4; ++m)
                #pragma unroll
                for (int n = 0; n < 4; ++n)
                    acc[m][n] = __builtin_amdgcn_mfma_f32_16x16x32_f16(af[m], bfr[n], acc[m][n], 0, 0, 0);
        }
        __syncthreads();
    }
    int q = l >> 4, cf = l & 15;
    #pragma unroll
    for (int m = 0; m < 4; ++m){
        #pragma unroll
        for (int n = 0; n < 4; ++n){
            int col = col0 + wcol*64 + n*16 + cf;
            float bv = bias[col];
            #pragma unroll
            for (int i = 0; i < 4; ++i){
                size_t r = row0 + wrow*64 + m*16 + q*4 + i;
                float v = acc[m][n][i] + bv;
                if (ACT == 1) v = gelu(v);
                if (OUTM == 1) ((ushort*)Cout)[r*N + col] = f2h(v);
                else           ((float*) Cout)[r*N + col] = v;
            }
        }
    }
}

// ============================ gate GEMM: fp8 ctx-segment + fp16 feats-segment ============================
__global__ __launch_bounds__(512, 4) void k_ggemm(const unsigned char* __restrict__ A8,
        const ushort* __restrict__ Af, const unsigned char* __restrict__ B8,
        const ushort* __restrict__ Bf, const float* __restrict__ bias,
        const float* __restrict__ Wg2, float* __restrict__ part){
    __shared__ alignas(16) unsigned char lds[49152];   // A 32KB + B 16KB
    unsigned char* As8 = lds;
    unsigned char* Bs8 = lds + 32768;
    ushort* As16 = (ushort*)lds;
    ushort* Bs16 = (ushort*)(lds + 32768);
    int t = threadIdx.x, l = t & 63, wv = t >> 6;
    int wrow = wv >> 1, wcol = wv & 1;
    constexpr int NX = 12;
    int nwg = NX * (int)gridDim.y;
    int orig = (int)blockIdx.y * NX + (int)blockIdx.x;
    int qq = nwg >> 3, rr = nwg & 7;
    int xcd = orig & 7, loc = orig >> 3;
    int wgid = (xcd < rr ? xcd*(qq+1) : rr*(qq+1) + (xcd-rr)*qq) + loc;
    int bx = wgid % NX;
    int by = wgid / NX;
    size_t row0 = (size_t)by * 256;
    int col0 = bx * 128;
    f32x4 acc[4][4] = {};
    int lrow = l >> 3;

    // ---- segment 1: fp8, K-tiles of 128 (ctx cols 0..1023) ----
    for (int kt = 0; kt < 8; ++kt){
        int k0 = kt << 7;
        #pragma unroll
        for (int i = 0; i < 4; ++i){
            int ch = wv*4 + i;
            int r  = ch*8 + lrow;
            gload_lds16(A8 + (row0 + r)*1024 + k0 + (l&7)*16, As8 + ch*1024);
        }
        #pragma unroll
        for (int i = 0; i < 2; ++i){
            int ch = wv*2 + i;
            int r  = ch*8 + lrow;
            gload_lds16(B8 + (size_t)(col0 + r)*1024 + k0 + (l&7)*16, Bs8 + ch*1024);
        }
        __syncthreads();
        #pragma unroll
        for (int kk = 0; kk < 4; ++kk){
            long a8[4], b8v[4];
            int j8 = (l >> 4) + kk*4;
            #pragma unroll
            for (int m = 0; m < 4; ++m){
                int row = wrow*64 + m*16 + (l & 15);
                int u = j8 ^ (row & 7);
                a8[m] = *(const long*)(const void*)(As8 + row*128 + u*8);
            }
            #pragma unroll
            for (int n = 0; n < 4; ++n){
                int col = wcol*64 + n*16 + (l & 15);
                int u = j8 ^ (col & 7);
                b8v[n] = *(const long*)(const void*)(Bs8 + col*128 + u*8);
            }
            #pragma unroll
            for (int m = 0; m < 4; ++m)
                #pragma unroll
                for (int n = 0; n < 4; ++n)
                    acc[m][n] = __builtin_amdgcn_mfma_f32_16x16x32_fp8_fp8(a8[m], b8v[n], acc[m][n], 0, 0, 0);
        }
        __syncthreads();
    }
    // ---- segment 2: fp16, K-tiles of 64 (feats cols 0..703) ----
    int lc8 = (l & 7) ^ lrow;
    for (int tt = 0; tt < 11; ++tt){
        int k0 = tt << 6;
        #pragma unroll
        for (int i = 0; i < 4; ++i){
            int ch = wv*4 + i;
            int r  = ch*8 + lrow;
            gload_lds16(Af + (row0 + r)*(size_t)F2D + k0 + lc8*8, As16 + ch*512);
        }
        #pragma unroll
        for (int i = 0; i < 2; ++i){
            int ch = wv*2 + i;
            int r  = ch*8 + lrow;
            gload_lds16(Bf + (size_t)(col0 + r)*F2D + k0 + lc8*8, Bs16 + ch*512);
        }
        __syncthreads();
        #pragma unroll
        for (int kk = 0; kk < 2; ++kk){
            f16x8 af[4], bfr[4];
            int j8 = kk*4 + (l >> 4);
            #pragma unroll
            for (int m = 0; m < 4; ++m){
                int row = wrow*64 + m*16 + (l & 15);
                int c16 = j8 ^ (row & 7);
                af[m] = *(const f16x8*)(const void*)(As16 + row*64 + c16*8);
            }
            #pragma unroll
            for (int n = 0; n < 4; ++n){
                int col = wcol*64 + n*16 + (l & 15);
                int c16 = j8 ^ (col & 7);
                bfr[n] = *(const f16x8*)(const void*)(Bs16 + col*64 + c16*8);
            }
            #pragma unroll
            for (int m = 0; m < 4; ++m)
                #pragma unroll
                for (int n = 0; n < 4; ++n)
                    acc[m][n] = __builtin_amdgcn_mfma_f32_16x16x32_f16(af[m], bfr[n], acc[m][n], 0, 0, 0);
        }
        __syncthreads();
    }
    // ---- fused gate head epilogue ----
    int q = l >> 4, cf = l & 15;
    float* sacc = (float*)lds;          // [256]
    if (t < 256) sacc[t] = 0.f;
    __syncthreads();
    #pragma unroll
    for (int m = 0; m < 4; ++m){
        #pragma unroll
        for (int i = 0; i < 4; ++i){
            float v = 0.f;
            #pragma unroll
            for (int n = 0; n < 4; ++n){
                int col = col0 + wcol*64 + n*16 + cf;
                float z = acc[m][n][i] + bias[col];
                v += gelu(z) * Wg2[col];
            }
            atomicAdd(&sacc[wrow*64 + m*16 + q*4 + i], v);
        }
    }
    __syncthreads();
    if (t < 256) part[(row0 + t)*NX + bx] = sacc[t];
}

// ============================ f32 GEMM, dynamic M, persistent grid (fix path) ============================
// GATHER=1: A rows gathered on-the-fly via flaglist
template<int ACT, int GATHER>
__global__ __launch_bounds__(256) void k_gemm_dyn(const float* __restrict__ A,
                                                  const float* __restrict__ W,
                                                  const float* __restrict__ bias,
                                                  float* __restrict__ C,
                                                  const int* __restrict__ cntp,
                                                  const int* __restrict__ flaglist,
                                                  int b0, int N, int K){
    int cnt = *cntp;
    int M = (cnt + 63) & ~63;
    __shared__ float As[32][68];
    __shared__ float Ws[32][64];
    int t  = threadIdx.x;
    int tx = t & 15, ty = t >> 4;
    int col0 = blockIdx.x * 64;
    int ra = t >> 3;
    int ca = (t & 7) << 2;
    int rw = t >> 4;
    int cw = (t & 15) << 2;
    for (int row0 = (int)blockIdx.y*64; row0 < M; row0 += (int)gridDim.y*64){
        float acc[4][4] = {};
        const float *Arow0, *Arow1;
        if (GATHER){
            int r1 = row0 + ra, r2 = r1 + 32;
            int f1 = (r1 < cnt) ? flaglist[r1] : 0;
            int f2 = (r2 < cnt) ? flaglist[r2] : 0;
            Arow0 = A + ((size_t)b0 + f1)*K;
            Arow1 = A + ((size_t)b0 + f2)*K;
        } else {
            Arow0 = A + (size_t)(row0 + ra)*K;
            Arow1 = A + (size_t)(row0 + ra + 32)*K;
        }
        for (int k0 = 0; k0 < K; k0 += 32){
            float4 a0 = *(const float4*)(Arow0 + k0 + ca);
            float4 a1 = *(const float4*)(Arow1 + k0 + ca);
            float4 w0 = *(const float4*)(W + (size_t)(k0 + rw)*N + col0 + cw);
            float4 w1 = *(const float4*)(W + (size_t)(k0 + rw + 16)*N + col0 + cw);
            As[ca+0][ra] = a0.x; As[ca+1][ra] = a0.y; As[ca+2][ra] = a0.z; As[ca+3][ra] = a0.w;
            As[ca+0][ra+32] = a1.x; As[ca+1][ra+32] = a1.y; As[ca+2][ra+32] = a1.z; As[ca+3][ra+32] = a1.w;
            *(float4*)&Ws[rw][cw]    = w0;
            *(float4*)&Ws[rw+16][cw] = w1;
            __syncthreads();
            #pragma unroll
            for (int kk = 0; kk < 32; ++kk){
                float4 av = *(const float4*)&As[kk][ty*4];
                float4 wv = *(const float4*)&Ws[kk][tx*4];
                float a4[4] = {av.x, av.y, av.z, av.w};
                float w4[4] = {wv.x, wv.y, wv.z, wv.w};
                #pragma unroll
                for (int i=0;i<4;i++)
                    #pragma unroll
                    for (int j=0;j<4;j++)
                        acc[i][j] = fmaf(a4[i], w4[j], acc[i][j]);
            }
            __syncthreads();
        }
        #pragma unroll
        for (int i=0;i<4;i++){
            size_t r = (size_t)row0 + ty*4 + i;
            #pragma unroll
            for (int j=0;j<4;j++){
                int c = col0 + tx*4 + j;
                float v = acc[i][j] + bias[c];
                if (ACT == 1) v = gelu(v);
                C[r*N + c] = v;
            }
        }
    }
}

// per flagged row: normalize exact ck, rescore, patch ckc/feats2/bidx
__global__ __launch_bounds__(256) void k_fixapply(const float* __restrict__ fck,
        const float* __restrict__ keys, const float* __restrict__ values,
        const float* __restrict__ age,  const float* __restrict__ alive,
        float* __restrict__ ckc, ushort* __restrict__ feats2, int* __restrict__ bidx,
        const int* __restrict__ flagcnt, const int* __restrict__ flaglist, int b0){
    int i = (blockIdx.x<<2) + (threadIdx.x>>6);
    int lane = threadIdx.x & 63;
    if (i >= *flagcnt) return;
    int w = flaglist[i];
    size_t b = (size_t)b0 + w;
    float2 c2 = ((const float2*)(fck + (size_t)i*128))[lane];
    float ss = c2.x*c2.x + c2.y*c2.y;
    #pragma unroll
    for (int o=32;o;o>>=1) ss += __shfl_xor(ss,o);
    float inv = 1.0f / fmaxf(sqrtf(ss), 1e-6f);
    float2 cc; cc.x = c2.x*inv; cc.y = c2.y*inv;
    ((float2*)(ckc + (size_t)w*128))[lane] = cc;
    ushort* f2 = feats2 + (size_t)w*F2D;
    { ushort2 o = { f2h(cc.x), f2h(cc.y) };
      ((ushort2*)f2)[lane] = o; }
    float s1v = -1e30f; int bi = 0; int anylive = 0;
    #pragma unroll
    for (int s=0;s<6;s++){
        float a = alive[b*6+s];
        float2 k2 = ((const float2*)(keys + (b*6+s)*128))[lane];
        float ks = k2.x*k2.x + k2.y*k2.y;
        float dt = cc.x*k2.x + cc.y*k2.y;
        #pragma unroll
        for (int o=32;o;o>>=1){ ks += __shfl_xor(ks,o); dt += __shfl_xor(dt,o); }
        float sc;
        if (a > 0.0f){ sc = dt / fmaxf(sqrtf(ks), 1e-6f); anylive = 1; }
        else sc = -1e4f;
        if (sc > s1v){ s1v = sc; bi = s; }
    }
    int bis = anylive ? bi : 0;
    float bsc = anylive ? s1v : 0.0f;
    float4 mv = ((const float4*)(values + (b*6+bis)*256))[lane];
    ushort4 mo = { f2h(mv.x), f2h(mv.y), f2h(mv.z), f2h(mv.w) };
    ((ushort4*)(f2+384))[lane] = mo;
    if (lane == 0){
        bidx[w] = bis;
        float mage = age[b*6 + bis];
        f2[640] = f2h(bsc);
        f2[641] = f2h(sigm((mage - 8.0f)*0.125f));
        f2[642] = f2h(1.0f - bsc);
    }
}

// ---- slot match + feats2 build + ambiguity flagging ----
__global__ __launch_bounds__(256) void k_feats(
        const float* __restrict__ ledger, const float* __restrict__ keys,
        const float* __restrict__ values, const float* __restrict__ age,
        const float* __restrict__ alive,  const float* __restrict__ ckv,
        float* __restrict__ ckc, ushort* __restrict__ feats2,
        int* __restrict__ bidx, int* __restrict__ flagcnt, int* __restrict__ flaglist,
        int b0){
    int w = (blockIdx.x<<2) + (threadIdx.x>>6);
    int lane = threadIdx.x & 63;
    size_t b = (size_t)b0 + w;
    const float* ckr = ckv + (size_t)w*384;
    float2 cr2 = ((const float2*)ckr)[lane];
    float ssc = cr2.x*cr2.x + cr2.y*cr2.y;
    #pragma unroll
    for (int o=32;o;o>>=1) ssc += __shfl_xor(ssc,o);
    float invc = 1.0f / fmaxf(sqrtf(ssc), 1e-6f);
    float2 cc; cc.x = cr2.x*invc; cc.y = cr2.y*invc;
    ((float2*)(ckc + (size_t)w*128))[lane] = cc;
    float s1v = -1e30f, s2v = -1e30f; int bi = 0; int anylive = 0;
    #pragma unroll
    for (int s=0;s<6;s++){
        float a = alive[b*6+s];
        float2 k2 = ((const float2*)(keys + (b*6+s)*128))[lane];
        float ss = k2.x*k2.x + k2.y*k2.y;
        float dt = cc.x*k2.x + cc.y*k2.y;
        #pragma unroll
        for (int o=32;o;o>>=1){ ss += __shfl_xor(ss,o); dt += __shfl_xor(dt,o); }
        float sc;
        if (a > 0.0f){ sc = dt / fmaxf(sqrtf(ss), 1e-6f); anylive = 1; }
        else sc = -1e4f;
        if (sc > s1v){ s2v = s1v; s1v = sc; bi = s; }
        else if (sc > s2v) s2v = sc;
    }
    float best_score = anylive ? s1v : 0.0f;
    int bis = anylive ? bi : 0;
    if (lane == 0 && (s1v - s2v) < TAU){
        int pos = atomicAdd(flagcnt, 1);
        flaglist[pos] = w;
    }
    float4 mv = ((const float4*)(values + (b*6+bis)*256))[lane];
    float mage = age[b*6+bis];
    float cad = sigm((mage - 8.0f)*0.125f);
    ushort* f2 = feats2 + (size_t)w*F2D;
    { ushort2 o = { f2h(cc.x), f2h(cc.y) };
      ((ushort2*)f2)[lane] = o; }
    { float4 v = ((const float4*)(ckr+128))[lane];
      ushort4 o = { f2h(v.x), f2h(v.y), f2h(v.z), f2h(v.w) };
      ((ushort4*)(f2+128))[lane] = o; }
    { ushort4 o = { f2h(mv.x), f2h(mv.y), f2h(mv.z), f2h(mv.w) };
      ((ushort4*)(f2+384))[lane] = o; }
    if (lane == 0){
        f2[640] = f2h(best_score);
        f2[641] = f2h(cad);
        f2[642] = f2h(1.0f - best_score);
        f2[643] = f2h(ledger[b*2]);
        f2[644] = f2h(ledger[b*2+1]);
        bidx[w] = bis;
    }
    if (lane < GPAD - GDIM) f2[645+lane] = 0;
}

// ---- gates (from part), spawn select, scatter update, summary ----
__global__ __launch_bounds__(256) void k_update(const float* __restrict__ keys,
        const float* __restrict__ values, const float* __restrict__ conf,
        const float* __restrict__ age,    const float* __restrict__ alive,
        const float* __restrict__ ckC,    const float* __restrict__ ckv,
        const float* __restrict__ part,   const float* __restrict__ bg2,
        const int* __restrict__ bidx,
        float* __restrict__ probsC,
        float* __restrict__ o_keys, float* __restrict__ o_vals,
        float* __restrict__ o_conf, float* __restrict__ o_age,
        float* __restrict__ o_aliv, float* __restrict__ o_sum,
        ushort* __restrict__ o_sumb, int b0){
    int w = (blockIdx.x<<2) + (threadIdx.x>>6);
    int lane = threadIdx.x & 63;
    size_t b = (size_t)b0 + w;
    const float* pp = part + (size_t)w*12;
    float pb[4];
    #pragma unroll
    for (int g=0; g<4; ++g)
        pb[g] = sigm(pp[3*g] + pp[3*g+1] + pp[3*g+2] + bg2[g]);
    if (lane < 4) probsC[w*4 + lane] = pb[lane];
    float rp = pb[0], sp = pb[1], tp = pb[3];
    float al[6], cf[6], ag[6];
    float hl = 0.f;
    #pragma unroll
    for (int s=0;s<6;s++){
        al[s]=alive[b*6+s]; cf[s]=conf[b*6+s]; ag[s]=age[b*6+s];
        hl = fmaxf(hl, al[s]);
    }
    float rr = hl * sigm((rp-0.55f)*4.0f);
    float sr = sigm((sp-0.60f)*4.0f);
    float den = 1.0f + rr + sr;
    float refresh = rr/den, spawn = sr/den;
    float retire = sigm((tp-0.15f)*4.0f);
    int bi = bidx[w];
    int ic = -1;
    #pragma unroll
    for (int s=5;s>=0;s--) if (al[s] < 0.5f) ic = s;
    int si;
    if (ic >= 0) si = ic;
    else {
        float bu = 1e30f; int am = 0;
        #pragma unroll
        for (int s=0;s<6;s++){
            float u = (s == bi) ? 1e4f : (cf[s] - 0.01f*ag[s]);
            if (u < bu){ bu = u; am = s; }
        }
        si = am;
    }
    float2 cc  = ((const float2*)(ckC + (size_t)w*128))[lane];
    float4 cvv = ((const float4*)(ckv + (size_t)w*384 + 128))[lane];
    float s0=0,s1=0,s2=0,s3=0, wsum=0;
    #pragma unroll
    for (int s=0;s<6;s++){
        float wr = refresh*(s==bi ? 1.0f:0.0f) + spawn*(s==si ? 1.0f:0.0f);
        wr = fminf(wr, 1.0f);
        float rs = (s==bi) ? retire : 0.0f;
        float om = 1.0f - wr;
        float2 k2 = ((const float2*)(keys + (b*6+s)*128))[lane];
        float2 kn; kn.x = k2.x*om + wr*cc.x; kn.y = k2.y*om + wr*cc.y;
        ((float2*)(o_keys + (b*6+s)*128))[lane] = kn;
        float4 vv = ((const float4*)(values + (b*6+s)*256))[lane];
        float4 vn;
        vn.x = vv.x*om + wr*cvv.x; vn.y = vv.y*om + wr*cvv.y;
        vn.z = vv.z*om + wr*cvv.z; vn.w = vv.w*om + wr*cvv.w;
        ((float4*)(o_vals + (b*6+s)*256))[lane] = vn;
        float cn  = (cf[s]*0.995f*om + wr) * (1.0f - rs);
        float an  = fminf(fmaxf(al[s]*(1.0f - rs) + wr, 0.0f), 1.0f);
        float agn = (ag[s] + al[s]) * om;
        float wgt = an * cn;
        wsum += wgt;
        s0 += vn.x*wgt; s1 += vn.y*wgt; s2 += vn.z*wgt; s3 += vn.w*wgt;
        if (lane == s){ o_conf[b*6+s] = cn; o_age[b*6+s] = agn; o_aliv[b*6+s] = an; }
    }
    float inv = 1.0f/(wsum + 1e-6f);
    float4 sm; sm.x = s0*inv; sm.y = s1*inv; sm.z = s2*inv; sm.w = s3*inv;
    ((float4*)(o_sum + b*256))[lane] = sm;
    ushort4 sb = { f2h(sm.x), f2h(sm.y), f2h(sm.z), f2h(sm.w) };
    ((ushort4*)(o_sumb + (size_t)w*256))[lane] = sb;
}

// ---- layernorm + promote (fp16 z in) ----
__global__ __launch_bounds__(256) void k_ln(const ushort* __restrict__ z,
        const float* __restrict__ probs, const float* __restrict__ g_ln,
        const float* __restrict__ b_ln,  float* __restrict__ o_prom, int b0){
    int w = blockIdx.x; int t = threadIdx.x;
    int lane = t & 63, wid = t >> 6;
    f16x4 hv = ((const f16x4*)(z + (size_t)w*1024))[t];
    float v0 = (float)hv[0], v1 = (float)hv[1], v2 = (float)hv[2], v3 = (float)hv[3];
    float s = v0+v1+v2+v3;
    #pragma unroll
    for (int o=32;o;o>>=1) s += __shfl_xor(s,o);
    __shared__ float red[4];
    if (lane==0) red[wid] = s;
    __syncthreads();
    float mu = (red[0]+red[1]+red[2]+red[3]) * (1.0f/1024.0f);
    float d0=v0-mu, d1=v1-mu, d2=v2-mu, d3=v3-mu;
    float ss = d0*d0+d1*d1+d2*d2+d3*d3;
    #pragma unroll
    for (int o=32;o;o>>=1) ss += __shfl_xor(ss,o);
    __syncthreads();
    if (lane==0) red[wid] = ss;
    __syncthreads();
    float var = (red[0]+red[1]+red[2]+red[3]) * (1.0f/1024.0f);
    float rstd = 1.0f / sqrtf(var + 1e-5f);
    float pm = sigm((probs[w*4+2]-0.50f)*4.0f);
    float4 g  = ((const float4*)g_ln)[t];
    float4 bb = ((const float4*)b_ln)[t];
    float4 o;
    o.x = pm*(d0*rstd*g.x + bb.x);
    o.y = pm*(d1*rstd*g.y + bb.y);
    o.z = pm*(d2*rstd*g.z + bb.z);
    o.w = pm*(d3*rstd*g.w + bb.w);
    ((float4*)(o_prom + ((size_t)b0 + w)*1024))[t] = o;
}

extern "C" void kernel_launch(void* const* d_in, const int* in_sizes, int n_in,
                              void* d_out, int out_size, void* d_ws, size_t ws_size,
                              hipStream_t stream){
    const float* ctx    = (const float*)d_in[0];
    const float* ledger = (const float*)d_in[1];
    const float* keys   = (const float*)d_in[2];
    const float* values = (const float*)d_in[3];
    const float* conf   = (const float*)d_in[4];
    const float* age    = (const float*)d_in[5];
    const float* alive  = (const float*)d_in[6];
    const float* Wk1 = (const float*)d_in[7];  const float* bk1 = (const float*)d_in[8];
    const float* Wk2 = (const float*)d_in[9];  const float* bk2 = (const float*)d_in[10];
    const float* Wv1 = (const float*)d_in[11]; const float* bv1 = (const float*)d_in[12];
    const float* Wv2 = (const float*)d_in[13]; const float* bv2 = (const float*)d_in[14];
    const float* Wg1 = (const float*)d_in[15]; const float* bg1 = (const float*)d_in[16];
    const float* Wg2 = (const float*)d_in[17]; const float* bg2 = (const float*)d_in[18];
    const float* Wsum= (const float*)d_in[19]; const float* bsum= (const float*)d_in[20];
    const float* g_ln= (const float*)d_in[21]; const float* b_ln= (const float*)d_in[22];

    float* out   = (float*)d_out;
    float* o_prom= out;
    float* o_sum = o_prom + (size_t)Bsz*Mdim;
    float* o_keys= o_sum  + (size_t)Bsz*Vdim;
    float* o_vals= o_keys + (size_t)Bsz*6*Kdim;
    float* o_conf= o_vals + (size_t)Bsz*6*Vdim;
    float* o_age = o_conf + (size_t)Bsz*6;
    float* o_aliv= o_age  + (size_t)Bsz*6;

    // ---------- workspace layout ----------
    char* p = (char*)d_ws;
    auto alloc = [&](size_t bytes)->char*{
        char* r = p; p += (bytes + 255) & ~(size_t)255; return r;
    };
    ushort* ctxh  = (ushort*)alloc((size_t)Bsz*Cdim*2);           // fp16 ctx
    unsigned char* ctx8 = (unsigned char*)alloc((size_t)Bsz*Cdim);// fp8 ctx, pre-swizzled
    ushort* W1m   = (ushort*)alloc((size_t)1024*Cdim*2);          // [Wk1t|Wv1t]
    ushort* W2m   = (ushort*)alloc((size_t)384*HMd*2);            // [Wk2t|Wv2t]
    unsigned char* Wg1t8 = (unsigned char*)alloc((size_t)GOUTd*1024); // fp8 gate ctx-part, pre-swz
    ushort* Wg1tf = (ushort*)alloc((size_t)GOUTd*F2D*2);          // fp16 gate feats-part
    ushort* Wsumt = (ushort*)alloc((size_t)Mdim*Vdim*2);
    float*  biasm1= (float*) alloc(1024*4);
    float*  biasm2= (float*) alloc(384*4);
    size_t fixed = (size_t)(p - (char*)d_ws);
    size_t per_row = 2048 + 1536 + 512 + 1408 + 48 + 4096 + 512 + 16
                   + 4 + 4 + 2048 + 512 + 128;
    int CB = 16384;
    while (CB > 256 && fixed + (size_t)CB*per_row + 16384 > ws_size) CB >>= 1;
    ushort* H      = (ushort*)alloc((size_t)CB*1024*2);   // [Hk|Hv] fp16
    float*  ckv    = (float*) alloc((size_t)CB*384*4);    // [ckraw|cv] f32
    float*  ckc    = (float*) alloc((size_t)CB*Kdim*4);
    ushort* feats2 = (ushort*)alloc((size_t)CB*F2D*2);
    float*  part   = (float*) alloc((size_t)CB*12*4);
    float*  zbuf   = (float*) alloc((size_t)CB*Mdim*4);
    ushort* sumb   = (ushort*)alloc((size_t)CB*Vdim*2);
    float*  probsC = (float*) alloc((size_t)CB*4*4);
    int*    bidxC  = (int*)   alloc((size_t)CB*4);
    int*    flagl  = (int*)   alloc((size_t)CB*4);
    int*    flagc  = (int*)   alloc(256);
    float*  fH     = (float*) alloc((size_t)CB*HMd*4);
    float*  fck    = (float*) alloc((size_t)CB*Kdim*4);
    ushort* zh     = (ushort*)zbuf;   // fp16 z view

    dim3 blk(256);
    dim3 blk512(512);
    // ---------- prep ----------
    k_cvt8<<<(int)(((size_t)Bsz*Cdim/8 + 255)/256), blk, 0, stream>>>(
        ctx, ctxh, ctx8, (int)((size_t)Bsz*Cdim/8));
    k_wt<<<dim3(HMd/64,  Cdim/64), blk, 0, stream>>>(Wk1, W1m,             Cdim, HMd);
    k_wt<<<dim3(HMd/64,  Cdim/64), blk, 0, stream>>>(Wv1, W1m + 512*Cdim,  Cdim, HMd);
    k_wt<<<dim3(Kdim/64, HMd/64),  blk, 0, stream>>>(Wk2, W2m,             HMd, Kdim);
    k_wt<<<dim3(Vdim/64, HMd/64),  blk, 0, stream>>>(Wv2, W2m + 128*HMd,   HMd, Vdim);
    k_wt<<<dim3(Mdim/64, Vdim/64), blk, 0, stream>>>(Wsum, Wsumt, Vdim, Mdim);
    k_wg1t8<<<dim3(6, 16, 4), blk, 0, stream>>>(Wg1, Wg1t8);
    k_wg1tf<<<dim3(6, 11, 4), blk, 0, stream>>>(Wg1, Wg1tf);
    k_cat<<<(1024+255)/256, blk, 0, stream>>>(biasm1, bk1, bv1, 512, 1024);
    k_cat<<<(384+255)/256,  blk, 0, stream>>>(biasm2, bk2, bv2, 128, 384);

    for (int b0 = 0; b0 < Bsz; b0 += CB){
        k_zero<<<1, blk, 0, stream>>>(flagc);
        // merged L1: H = gelu(ctx @ [Wk1|Wv1] + [bk1|bv1]), fp16 out
        k_mgemm<1,1,0,8><<<dim3(8, CB/256), blk512, 0, stream>>>(
            ctxh + (size_t)b0*Cdim, nullptr, W1m, biasm1, nullptr, H, Cdim, Cdim);
        // merged L2: ckv = [Hk@Wk2+bk2 | Hv@Wv2+bv2], f32 out
        k_mgemm<0,0,2,3><<<dim3(3, CB/256), blk512, 0, stream>>>(
            H, nullptr, W2m, biasm2, nullptr, ckv, HMd, 1024);
        // slot match + feats2 + flags
        k_feats<<<CB/4, blk, 0, stream>>>(ledger, keys, values, age, alive,
                                          ckv, ckc, feats2, bidxC, flagc, flagl, b0);
        // exact f32 recompute of ambiguous rows (gathered A, persistent grids)
        k_gemm_dyn<1,1><<<dim3(HMd/64, 16), blk, 0, stream>>>(
            ctx, Wk1, bk1, fH, flagc, flagl, b0, HMd, Cdim);
        k_gemm_dyn<0,0><<<dim3(Kdim/64, 16), blk, 0, stream>>>(
            fH, Wk2, bk2, fck, flagc, nullptr, 0, Kdim, HMd);
        k_fixapply<<<CB/4, blk, 0, stream>>>(fck, keys, values, age, alive,
                                             ckc, feats2, bidxC, flagc, flagl, b0);
        // gate GEMM (fp8 ctx-segment + fp16 feats-segment) with fused head: part[b,12]
        k_ggemm<<<dim3(12, CB/256), blk512, 0, stream>>>(
            ctx8 + (size_t)b0*Cdim, feats2, Wg1t8, Wg1tf, bg1, Wg2, part);
        // gates + scatter update + summary
        k_update<<<CB/4, blk, 0, stream>>>(keys, values, conf, age, alive, ckc, ckv,
                                           part, bg2, bidxC, probsC,
                                           o_keys, o_vals, o_conf, o_age, o_aliv,
                                           o_sum, sumb, b0);
        // summary projection (fp16 z out) + LN + promote
        k_mgemm<0,1,0,8><<<dim3(8, CB/256), blk512, 0, stream>>>(
            sumb, nullptr, Wsumt, bsum, nullptr, zh, Vdim, Vdim);
        k_ln<<<CB, blk, 0, stream>>>(zh, probsC, g_ln, b_ln, o_prom, b0);
    }
}